// Round 9
// baseline (842.762 us; speedup 1.0000x reference)
//
#include <hip/hip_runtime.h>

#define TT   365
#define BTOT 2048
#define DIN  32
#define SIN  27
#define HD   256
#define G3   768
#define BLOCK 512
#define ZBUF 4608
#define XOFF 4096
#define WIHL_OFF 9216
#define SMEM_SZ  (WIHL_OFF + G3*64)   // 58368
#define L2E  1.442695040888963f

// ws layout (all written by prep): whh_bf16 | wih_bf16 | bias_scaled_f32
#define WS_WIH  (G3*HD*2)            // 393216
#define WS_BIAS (WS_WIH + G3*DIN*2)  // 442368

typedef float  f32x4  __attribute__((ext_vector_type(4)));
typedef short  bf16x8 __attribute__((ext_vector_type(8)));
typedef unsigned int u32x2 __attribute__((ext_vector_type(2)));

__device__ __forceinline__ unsigned short f2bf(float f) {
  unsigned u = __builtin_bit_cast(unsigned, f);
  u += 0x7fffu + ((u >> 16) & 1u);          // RNE to bf16
  return (unsigned short)(u >> 16);
}
__device__ __forceinline__ float bf2f(unsigned short u) {
  unsigned v = ((unsigned)u) << 16;
  return __builtin_bit_cast(float, v);
}

// prep: bf16-quantize weights with log2e folded (f,o rows x L2E; g rows x 2*L2E),
// and prescale bias the same way.
__global__ void prep_kernel(const float* __restrict__ whh, const float* __restrict__ wih,
                            const float* __restrict__ bias,
                            unsigned short* __restrict__ whh_bf,
                            unsigned short* __restrict__ wih_bf,
                            float* __restrict__ bias_s) {
  int stride = gridDim.x * blockDim.x;
  int i0 = blockIdx.x * blockDim.x + threadIdx.x;
  for (int i = i0; i < G3 * HD; i += stride) {
    int row = i >> 8;
    float s = (row >= HD && row < 2 * HD) ? 2.0f * L2E : L2E;
    whh_bf[i] = f2bf(whh[i] * s);
  }
  for (int i = i0; i < G3 * DIN; i += stride) {
    int row = i >> 5;
    float s = (row >= HD && row < 2 * HD) ? 2.0f * L2E : L2E;
    wih_bf[i] = f2bf(wih[i] * s);
  }
  for (int i = i0; i < G3; i += stride) {
    float s = (i >= HD && i < 2 * HD) ? 2.0f * L2E : L2E;
    bias_s[i] = bias[i] * s;
  }
}

// Persistent block per 8 batch rows, transposed orientation:
// gates^T(768 x 8) = Whh~ (A, gate-rows) x h^T (B, cols=batch, LDS).
// ALL 8 Whh k-octets pinned in registers via asm opaque barrier (192 VGPR);
// Wih in LDS (rotation-swizzled). One barrier per step.
// D: row=q*4+r = gate-row j, col=m = batch (m>=8 dup -> 'half' col-slice).
__global__ void __launch_bounds__(BLOCK, 2)
ealstm_kernel(const float* __restrict__ x_dd, const float* __restrict__ x_s,
              const float* __restrict__ w_in, const float* __restrict__ b_in,
              const float* __restrict__ w_dense, const float* __restrict__ b_dense,
              const unsigned short* __restrict__ whh_bf,
              const unsigned short* __restrict__ wih_bf,
              const float* __restrict__ bias_s,
              float* __restrict__ out) {
  __shared__ __attribute__((aligned(16))) char sm[SMEM_SZ];   // 57 KB
  char* zb   = sm;             // 2 x 4608: h (4096) + x (512) per buffer
  char* wihl = sm + WIHL_OFF;  // Wih~ rows, 64B stride, rot-swizzled octets

  const int tid  = threadIdx.x;
  const int b0   = blockIdx.x * 8;
  const int w    = tid >> 6;
  const int lane = tid & 63;
  const int m    = lane & 15;
  const int q    = lane >> 4;
  const int b    = m & 7;
  const int half = m >> 3;

  // stage Wih~ into LDS: row r octet qq at r*64 + rot(qq,r)
  for (int i = tid; i < G3 * 4; i += BLOCK) {
    int row = i >> 2, qq = i & 3;
    int rot = ((qq + ((row >> 1) & 3)) & 3) << 4;
    *(bf16x8*)(wihl + row * 64 + rot) = *(const bf16x8*)(wih_bf + row * DIN + qq * 8);
  }
  // zero h of buffer 0
  if (tid < 256) *(f32x4*)(zb + tid * 16) = f32x4{0.f, 0.f, 0.f, 0.f};

  // x staging slot (rotation-swizzled octets): row xr_, elem xd
  const bool xthr = tid < 256;
  const int xr_ = (tid >> 5) & 7, xd = tid & 31;
  const int xso = XOFF + xr_ * 64 + ((((xd >> 3) + (xr_ >> 1)) & 3) << 4) + (xd & 7) * 2;
  const float* xq = x_dd + (size_t)(b0 + xr_) * DIN + xd;
  if (xthr) *(unsigned short*)(zb + xso) = f2bf(xq[0]);   // x(0) -> buf0
  xq += (size_t)BTOT * DIN;                               // -> x(1)

  // Whh~ A-fragments kk=0..7 ALL in registers (forced residency via asm barrier)
  const int sb0 = w * 16;
  int sbs[6];
  bf16x8 wr[6][8];
  #pragma unroll
  for (int s = 0; s < 6; ++s) {
    int sbase = sb0 + (s >= 3 ? 128 : 0) + (s % 3) * 256;
    sbs[s] = sbase;
    const unsigned short* wp = whh_bf + (size_t)(sbase + m) * HD + q * 8;
    #pragma unroll
    for (int kk = 0; kk < 8; ++kk) wr[s][kk] = *(const bf16x8*)(wp + kk * 32);
  }
  #pragma unroll
  for (int s = 0; s < 6; ++s)
    #pragma unroll
    for (int kk = 0; kk < 8; ++kk)
      asm volatile("" : "+v"(wr[s][kk]));   // opaque: no remat, must stay resident

  // per-lane (j, b) mapping: j = j0 + r, batch = b
  const int j0 = sb0 + half * 128 + q * 4;
  float cst[4], ig[4];
  #pragma unroll
  for (int r = 0; r < 4; ++r) {
    int j = j0 + r;
    float a = b_in[j];
    const float* xr = x_s + (size_t)(b0 + b) * SIN;
    const float* wn = w_in + (size_t)j * SIN;
    #pragma unroll
    for (int ss = 0; ss < SIN; ++ss) a += xr[ss] * wn[ss];
    ig[r] = __builtin_amdgcn_rcpf(1.0f + __builtin_amdgcn_exp2f(-a * L2E));
    cst[r] = 0.0f;
  }

  const int swz = b << 4;
  const int wro = ((q + ((m >> 1) & 3)) & 3) << 4;              // LDS weight read rot
  const int xrd = XOFF + b * 64 + (((q + (b >> 1)) & 3) << 4);  // x B-frag read
  const int hrb = b * 512;
  const int hq  = q * 16;
  const int hw  = b * 512 + ((j0 * 2) ^ swz);                   // h write (rel. buffer)
  const float* bfp = bias_s + j0;
  const float* bgp = bias_s + 256 + j0;
  const float* bop = bias_s + 512 + j0;

  const f32x4 z4 = f32x4{0.f, 0.f, 0.f, 0.f};
  __syncthreads();

  for (int t = 0; t < TT; ++t) {
    char* zc = zb + (t & 1) * ZBUF;
    char* zn = zb + ((t + 1) & 1) * ZBUF;

    float xv = 0.0f;
    if (xthr && t + 1 < TT) xv = xq[0];
    f32x4 bf4 = *(const f32x4*)bfp;                  // L1-hit (prescaled bias)
    f32x4 bg4 = *(const f32x4*)bgp;
    f32x4 bo4 = *(const f32x4*)bop;

    // ---- MFMA chain: x-part (C=0, LDS Wih), then kk=0..7 from registers ----
    bf16x8 xf = *(const bf16x8*)(zc + xrd);
    f32x4 acc0, acc1, acc2, acc3, acc4, acc5;
    {
      bf16x8 w0 = *(const bf16x8*)(wihl + (sbs[0] + m) * 64 + wro);
      bf16x8 w1 = *(const bf16x8*)(wihl + (sbs[1] + m) * 64 + wro);
      bf16x8 w2 = *(const bf16x8*)(wihl + (sbs[2] + m) * 64 + wro);
      bf16x8 w3 = *(const bf16x8*)(wihl + (sbs[3] + m) * 64 + wro);
      bf16x8 w4 = *(const bf16x8*)(wihl + (sbs[4] + m) * 64 + wro);
      bf16x8 w5 = *(const bf16x8*)(wihl + (sbs[5] + m) * 64 + wro);
      acc0 = __builtin_amdgcn_mfma_f32_16x16x32_bf16(w0, xf, z4, 0, 0, 0);
      acc1 = __builtin_amdgcn_mfma_f32_16x16x32_bf16(w1, xf, z4, 0, 0, 0);
      acc2 = __builtin_amdgcn_mfma_f32_16x16x32_bf16(w2, xf, z4, 0, 0, 0);
      acc3 = __builtin_amdgcn_mfma_f32_16x16x32_bf16(w3, xf, z4, 0, 0, 0);
      acc4 = __builtin_amdgcn_mfma_f32_16x16x32_bf16(w4, xf, z4, 0, 0, 0);
      acc5 = __builtin_amdgcn_mfma_f32_16x16x32_bf16(w5, xf, z4, 0, 0, 0);
    }
    #pragma unroll
    for (int kk = 0; kk < 8; ++kk) {
      bf16x8 hf = *(const bf16x8*)(zc + hrb + ((kk * 64 + hq) ^ swz));
      acc0 = __builtin_amdgcn_mfma_f32_16x16x32_bf16(wr[0][kk], hf, acc0, 0, 0, 0);
      acc1 = __builtin_amdgcn_mfma_f32_16x16x32_bf16(wr[1][kk], hf, acc1, 0, 0, 0);
      acc2 = __builtin_amdgcn_mfma_f32_16x16x32_bf16(wr[2][kk], hf, acc2, 0, 0, 0);
      acc3 = __builtin_amdgcn_mfma_f32_16x16x32_bf16(wr[3][kk], hf, acc3, 0, 0, 0);
      acc4 = __builtin_amdgcn_mfma_f32_16x16x32_bf16(wr[4][kk], hf, acc4, 0, 0, 0);
      acc5 = __builtin_amdgcn_mfma_f32_16x16x32_bf16(wr[5][kk], hf, acc5, 0, 0, 0);
    }

    // ---- elementwise (pre-activations prescaled by log2e; 2*log2e for g) ----
    float h0, h1, h2, h3;
    #pragma unroll
    for (int r = 0; r < 4; ++r) {
      float pf = (half ? acc3[r] : acc0[r]) + bf4[r];
      float pg = (half ? acc4[r] : acc1[r]) + bg4[r];
      float po = (half ? acc5[r] : acc2[r]) + bo4[r];
      float fg = __builtin_amdgcn_rcpf(1.0f + __builtin_amdgcn_exp2f(-pf));
      float gg = 1.0f - 2.0f * __builtin_amdgcn_rcpf(1.0f + __builtin_amdgcn_exp2f(pg));
      float og = __builtin_amdgcn_rcpf(1.0f + __builtin_amdgcn_exp2f(-po));
      float c  = fg * cst[r] + ig[r] * gg;
      cst[r] = c;
      float th = 1.0f - 2.0f * __builtin_amdgcn_rcpf(1.0f + __builtin_amdgcn_exp2f(c * (2.0f * L2E)));
      float hv = og * th;
      if (r == 0) h0 = hv; else if (r == 1) h1 = hv; else if (r == 2) h2 = hv; else h3 = hv;
    }
    unsigned pk0, pk1;
    asm("v_cvt_pk_bf16_f32 %0, %1, %2" : "=v"(pk0) : "v"(h0), "v"(h1));
    asm("v_cvt_pk_bf16_f32 %0, %1, %2" : "=v"(pk1) : "v"(h2), "v"(h3));
    u32x2 pk = u32x2{pk0, pk1};
    *(u32x2*)(zn + hw) = pk;                         // one ds_write_b64

    if (xthr && t + 1 < TT) {
      *(unsigned short*)(zn + xso) = f2bf(xv);
      xq += (size_t)BTOT * DIN;
    }
    __syncthreads();
  }

  // ---- output: out[b] = sum_j h[b][j] * w_dense[j] + b_dense[0] ----
  if (tid < 64) {
    const char* hb = zb + (TT & 1) * ZBUF;           // TT=365 -> buffer 1
    int row = tid >> 3, seg = tid & 7;
    float sum = 0.0f;
    #pragma unroll
    for (int jj = 0; jj < 32; ++jj) {
      int j = seg * 32 + jj;
      unsigned short hu = *(const unsigned short*)(hb + row * 512 + ((j * 2) ^ (row << 4)));
      sum += bf2f(hu) * w_dense[j];
    }
    sum += __shfl_xor(sum, 1, 64);
    sum += __shfl_xor(sum, 2, 64);
    sum += __shfl_xor(sum, 4, 64);
    if (seg == 0) out[b0 + row] = sum + b_dense[0];
  }
}

extern "C" void kernel_launch(void* const* d_in, const int* in_sizes, int n_in,
                              void* d_out, int out_size, void* d_ws, size_t ws_size,
                              hipStream_t stream) {
  (void)in_sizes; (void)n_in; (void)out_size; (void)ws_size;
  const float* x_dd = (const float*)d_in[0];
  const float* x_s  = (const float*)d_in[1];
  const float* wih  = (const float*)d_in[2];
  const float* whh  = (const float*)d_in[3];
  const float* bias = (const float*)d_in[4];
  const float* w_in = (const float*)d_in[5];
  const float* b_in = (const float*)d_in[6];
  const float* w_d  = (const float*)d_in[7];
  const float* b_d  = (const float*)d_in[8];
  float* out = (float*)d_out;
  unsigned char* ws = (unsigned char*)d_ws;

  unsigned short* whh_bf = (unsigned short*)ws;
  unsigned short* wih_bf = (unsigned short*)(ws + WS_WIH);
  float*          bias_s = (float*)(ws + WS_BIAS);

  prep_kernel<<<128, 256, 0, stream>>>(whh, wih, bias, whh_bf, wih_bf, bias_s);
  ealstm_kernel<<<BTOT / 8, BLOCK, 0, stream>>>(
      x_dd, x_s, w_in, b_in, w_d, b_d, whh_bf, wih_bf, bias_s, out);
}

// Round 10
// 624.257 us; speedup vs baseline: 1.3500x; 1.3500x over previous
//
#include <hip/hip_runtime.h>

#define TT   365
#define BTOT 2048
#define DIN  32
#define SIN  27
#define HD   256
#define G3   768
#define BLOCK 512
#define ZBUF 4096
#define WIHL_OFF 8192
#define WHH7_OFF (WIHL_OFF + G3*64)   // 57344
#define SMEM_SZ  (WHH7_OFF + G3*64)   // 106496
#define L2E  1.442695040888963f

// ws layout (all written by prep): whh_bf16 | wih_bf16 | bias_scaled_f32
#define WS_WIH  (G3*HD*2)            // 393216
#define WS_BIAS (WS_WIH + G3*DIN*2)  // 442368

typedef float  f32x4  __attribute__((ext_vector_type(4)));
typedef short  bf16x8 __attribute__((ext_vector_type(8)));
typedef unsigned int u32x2 __attribute__((ext_vector_type(2)));
typedef unsigned int u32x4 __attribute__((ext_vector_type(4)));

__device__ __forceinline__ unsigned short f2bf(float f) {
  unsigned u = __builtin_bit_cast(unsigned, f);
  u += 0x7fffu + ((u >> 16) & 1u);          // RNE to bf16
  return (unsigned short)(u >> 16);
}
__device__ __forceinline__ float bf2f(unsigned short u) {
  unsigned v = ((unsigned)u) << 16;
  return __builtin_bit_cast(float, v);
}
__device__ __forceinline__ bf16x8 cvt8(f32x4 a, f32x4 c) {
  unsigned c0, c1, c2, c3;
  asm("v_cvt_pk_bf16_f32 %0, %1, %2" : "=v"(c0) : "v"(a[0]), "v"(a[1]));
  asm("v_cvt_pk_bf16_f32 %0, %1, %2" : "=v"(c1) : "v"(a[2]), "v"(a[3]));
  asm("v_cvt_pk_bf16_f32 %0, %1, %2" : "=v"(c2) : "v"(c[0]), "v"(c[1]));
  asm("v_cvt_pk_bf16_f32 %0, %1, %2" : "=v"(c3) : "v"(c[2]), "v"(c[3]));
  u32x4 u = u32x4{c0, c1, c2, c3};
  return __builtin_bit_cast(bf16x8, u);
}

// prep: bf16-quantize weights with log2e folded (f,o rows x L2E; g rows x 2*L2E),
// and prescale bias the same way.
__global__ void prep_kernel(const float* __restrict__ whh, const float* __restrict__ wih,
                            const float* __restrict__ bias,
                            unsigned short* __restrict__ whh_bf,
                            unsigned short* __restrict__ wih_bf,
                            float* __restrict__ bias_s) {
  int stride = gridDim.x * blockDim.x;
  int i0 = blockIdx.x * blockDim.x + threadIdx.x;
  for (int i = i0; i < G3 * HD; i += stride) {
    int row = i >> 8;
    float s = (row >= HD && row < 2 * HD) ? 2.0f * L2E : L2E;
    whh_bf[i] = f2bf(whh[i] * s);
  }
  for (int i = i0; i < G3 * DIN; i += stride) {
    int row = i >> 5;
    float s = (row >= HD && row < 2 * HD) ? 2.0f * L2E : L2E;
    wih_bf[i] = f2bf(wih[i] * s);
  }
  for (int i = i0; i < G3; i += stride) {
    float s = (i >= HD && i < 2 * HD) ? 2.0f * L2E : L2E;
    bias_s[i] = bias[i] * s;
  }
}

// Persistent block per 8 batch rows, transposed orientation:
// gates^T(768 x 8) = Whh~ (A, gate-rows) x h^T (B, cols=batch, LDS).
// Whh kk=0..6 pinned in registers (168 VGPR, asm opaque barrier); kk=7 + Wih
// in LDS (rotation-swizzled). x lives in per-lane REGISTERS (global->reg->cvt),
// and the x-projection MFMAs for step t+1 run in step t's EW tail (they depend
// only on x and step-invariant weights, not on h), shortening the post-barrier
// critical path. One barrier per step.
__global__ void __launch_bounds__(BLOCK, 2)
ealstm_kernel(const float* __restrict__ x_dd, const float* __restrict__ x_s,
              const float* __restrict__ w_in, const float* __restrict__ b_in,
              const float* __restrict__ w_dense, const float* __restrict__ b_dense,
              const unsigned short* __restrict__ whh_bf,
              const unsigned short* __restrict__ wih_bf,
              const float* __restrict__ bias_s,
              float* __restrict__ out) {
  __shared__ __attribute__((aligned(16))) char sm[SMEM_SZ];   // 104 KB
  char* zb    = sm;             // 2 x 4096: h double buffer
  char* wihl  = sm + WIHL_OFF;  // Wih~ rows, 64B stride, rot-swizzled octets
  char* whh7l = sm + WHH7_OFF;  // Whh~ kk=7 octets, same layout

  const int tid  = threadIdx.x;
  const int b0   = blockIdx.x * 8;
  const int w    = tid >> 6;
  const int lane = tid & 63;
  const int m    = lane & 15;
  const int q    = lane >> 4;
  const int b    = m & 7;
  const int half = m >> 3;

  // stage Wih~ and Whh~[kk=7] into LDS: row r octet qq at r*64 + rot(qq,r)
  for (int i = tid; i < G3 * 4; i += BLOCK) {
    int row = i >> 2, qq = i & 3;
    int rot = ((qq + ((row >> 1) & 3)) & 3) << 4;
    *(bf16x8*)(wihl + row * 64 + rot)  = *(const bf16x8*)(wih_bf + row * DIN + qq * 8);
    *(bf16x8*)(whh7l + row * 64 + rot) =
        *(const bf16x8*)(whh_bf + (size_t)row * HD + 7 * 32 + qq * 8);
  }
  // zero h of buffer 0
  if (tid < 256) *(f32x4*)(zb + tid * 16) = f32x4{0.f, 0.f, 0.f, 0.f};

  // per-lane x source: 8 consecutive f32 of x_dd[t][b0+b][q*8..]
  const float* xp = x_dd + ((size_t)(b0 + b)) * DIN + q * 8;
  f32x4 xa = *(const f32x4*)xp;
  f32x4 xc = *(const f32x4*)(xp + 4);
  xp += (size_t)BTOT * DIN;                 // -> t=1

  // Whh~ A-fragments kk=0..6 in registers (forced residency via asm barrier)
  const int sb0 = w * 16;
  int sbs[6];
  bf16x8 wr[6][7];
  #pragma unroll
  for (int s = 0; s < 6; ++s) {
    int sbase = sb0 + (s >= 3 ? 128 : 0) + (s % 3) * 256;
    sbs[s] = sbase;
    const unsigned short* wp = whh_bf + (size_t)(sbase + m) * HD + q * 8;
    #pragma unroll
    for (int kk = 0; kk < 7; ++kk) wr[s][kk] = *(const bf16x8*)(wp + kk * 32);
  }
  #pragma unroll
  for (int s = 0; s < 6; ++s)
    #pragma unroll
    for (int kk = 0; kk < 7; ++kk)
      asm volatile("" : "+v"(wr[s][kk]));   // opaque: no remat, must stay resident

  // per-lane (j, b) mapping: j = j0 + r, batch = b
  const int j0 = sb0 + half * 128 + q * 4;
  float cst[4], ig[4];
  #pragma unroll
  for (int r = 0; r < 4; ++r) {
    int j = j0 + r;
    float a = b_in[j];
    const float* xr = x_s + (size_t)(b0 + b) * SIN;
    const float* wn = w_in + (size_t)j * SIN;
    #pragma unroll
    for (int ss = 0; ss < SIN; ++ss) a += xr[ss] * wn[ss];
    ig[r] = __builtin_amdgcn_rcpf(1.0f + __builtin_amdgcn_exp2f(-a * L2E));
    cst[r] = 0.0f;
  }

  const int swz = b << 4;
  const int wro = ((q + ((m >> 1) & 3)) & 3) << 4;              // LDS weight read rot
  const int hrb = b * 512;
  const int hq  = q * 16;
  const int hw  = b * 512 + ((j0 * 2) ^ swz);                   // h write (rel. buffer)
  const float* bfp = bias_s + j0;
  const float* bgp = bias_s + 256 + j0;
  const float* bop = bias_s + 512 + j0;

  const f32x4 z4 = f32x4{0.f, 0.f, 0.f, 0.f};
  __syncthreads();

  f32x4 acc0, acc1, acc2, acc3, acc4, acc5;
  {   // x-projection for t=0 (C=0; bias added in EW)
    bf16x8 xf = cvt8(xa, xc);
    bf16x8 w0 = *(const bf16x8*)(wihl + (sbs[0] + m) * 64 + wro);
    bf16x8 w1 = *(const bf16x8*)(wihl + (sbs[1] + m) * 64 + wro);
    bf16x8 w2 = *(const bf16x8*)(wihl + (sbs[2] + m) * 64 + wro);
    bf16x8 w3 = *(const bf16x8*)(wihl + (sbs[3] + m) * 64 + wro);
    bf16x8 w4 = *(const bf16x8*)(wihl + (sbs[4] + m) * 64 + wro);
    bf16x8 w5 = *(const bf16x8*)(wihl + (sbs[5] + m) * 64 + wro);
    acc0 = __builtin_amdgcn_mfma_f32_16x16x32_bf16(w0, xf, z4, 0, 0, 0);
    acc1 = __builtin_amdgcn_mfma_f32_16x16x32_bf16(w1, xf, z4, 0, 0, 0);
    acc2 = __builtin_amdgcn_mfma_f32_16x16x32_bf16(w2, xf, z4, 0, 0, 0);
    acc3 = __builtin_amdgcn_mfma_f32_16x16x32_bf16(w3, xf, z4, 0, 0, 0);
    acc4 = __builtin_amdgcn_mfma_f32_16x16x32_bf16(w4, xf, z4, 0, 0, 0);
    acc5 = __builtin_amdgcn_mfma_f32_16x16x32_bf16(w5, xf, z4, 0, 0, 0);
  }

  for (int t = 0; t < TT; ++t) {
    char* zc = zb + (t & 1) * ZBUF;
    char* zn = zb + ((t + 1) & 1) * ZBUF;
    const bool more = (t + 1 < TT);

    f32x4 bf4 = *(const f32x4*)bfp;                  // L1-hit (prescaled bias)
    f32x4 bg4 = *(const f32x4*)bgp;
    f32x4 bo4 = *(const f32x4*)bop;

    // ---- recurrent MFMA chain: kk=0..6 from registers, kk=7 from LDS ----
    #pragma unroll
    for (int kk = 0; kk < 7; ++kk) {
      bf16x8 hf = *(const bf16x8*)(zc + hrb + ((kk * 64 + hq) ^ swz));
      acc0 = __builtin_amdgcn_mfma_f32_16x16x32_bf16(wr[0][kk], hf, acc0, 0, 0, 0);
      acc1 = __builtin_amdgcn_mfma_f32_16x16x32_bf16(wr[1][kk], hf, acc1, 0, 0, 0);
      acc2 = __builtin_amdgcn_mfma_f32_16x16x32_bf16(wr[2][kk], hf, acc2, 0, 0, 0);
      acc3 = __builtin_amdgcn_mfma_f32_16x16x32_bf16(wr[3][kk], hf, acc3, 0, 0, 0);
      acc4 = __builtin_amdgcn_mfma_f32_16x16x32_bf16(wr[4][kk], hf, acc4, 0, 0, 0);
      acc5 = __builtin_amdgcn_mfma_f32_16x16x32_bf16(wr[5][kk], hf, acc5, 0, 0, 0);
    }
    {   // kk = 7 from LDS
      bf16x8 hf = *(const bf16x8*)(zc + hrb + ((7 * 64 + hq) ^ swz));
      bf16x8 u0 = *(const bf16x8*)(whh7l + (sbs[0] + m) * 64 + wro);
      bf16x8 u1 = *(const bf16x8*)(whh7l + (sbs[1] + m) * 64 + wro);
      bf16x8 u2 = *(const bf16x8*)(whh7l + (sbs[2] + m) * 64 + wro);
      bf16x8 u3 = *(const bf16x8*)(whh7l + (sbs[3] + m) * 64 + wro);
      bf16x8 u4 = *(const bf16x8*)(whh7l + (sbs[4] + m) * 64 + wro);
      bf16x8 u5 = *(const bf16x8*)(whh7l + (sbs[5] + m) * 64 + wro);
      acc0 = __builtin_amdgcn_mfma_f32_16x16x32_bf16(u0, hf, acc0, 0, 0, 0);
      acc1 = __builtin_amdgcn_mfma_f32_16x16x32_bf16(u1, hf, acc1, 0, 0, 0);
      acc2 = __builtin_amdgcn_mfma_f32_16x16x32_bf16(u2, hf, acc2, 0, 0, 0);
      acc3 = __builtin_amdgcn_mfma_f32_16x16x32_bf16(u3, hf, acc3, 0, 0, 0);
      acc4 = __builtin_amdgcn_mfma_f32_16x16x32_bf16(u4, hf, acc4, 0, 0, 0);
      acc5 = __builtin_amdgcn_mfma_f32_16x16x32_bf16(u5, hf, acc5, 0, 0, 0);
    }

    // ---- EW1: f,g,c-update ----
    #pragma unroll
    for (int r = 0; r < 4; ++r) {
      float pf = (half ? acc3[r] : acc0[r]) + bf4[r];
      float pg = (half ? acc4[r] : acc1[r]) + bg4[r];
      float fg = __builtin_amdgcn_rcpf(1.0f + __builtin_amdgcn_exp2f(-pf));
      float gg = 1.0f - 2.0f * __builtin_amdgcn_rcpf(1.0f + __builtin_amdgcn_exp2f(pg));
      cst[r] = fg * cst[r] + ig[r] * gg;
    }

    // issue x(t+1) global loads (cover under EW2)
    if (more) {
      xa = *(const f32x4*)xp;
      xc = *(const f32x4*)(xp + 4);
      xp += (size_t)BTOT * DIN;
    }

    // ---- EW2: o, tanh(c), h pack/write ----
    float h0, h1, h2, h3;
    #pragma unroll
    for (int r = 0; r < 4; ++r) {
      float po = (half ? acc5[r] : acc2[r]) + bo4[r];
      float og = __builtin_amdgcn_rcpf(1.0f + __builtin_amdgcn_exp2f(-po));
      float th = 1.0f - 2.0f * __builtin_amdgcn_rcpf(1.0f + __builtin_amdgcn_exp2f(cst[r] * (2.0f * L2E)));
      float hv = og * th;
      if (r == 0) h0 = hv; else if (r == 1) h1 = hv; else if (r == 2) h2 = hv; else h3 = hv;
    }
    unsigned pk0, pk1;
    asm("v_cvt_pk_bf16_f32 %0, %1, %2" : "=v"(pk0) : "v"(h0), "v"(h1));
    asm("v_cvt_pk_bf16_f32 %0, %1, %2" : "=v"(pk1) : "v"(h2), "v"(h3));
    u32x2 pk = u32x2{pk0, pk1};
    *(u32x2*)(zn + hw) = pk;                         // one ds_write_b64

    // ---- x-projection for t+1 in the tail (no h dependency) ----
    if (more) {
      bf16x8 xf = cvt8(xa, xc);
      bf16x8 w0 = *(const bf16x8*)(wihl + (sbs[0] + m) * 64 + wro);
      bf16x8 w1 = *(const bf16x8*)(wihl + (sbs[1] + m) * 64 + wro);
      bf16x8 w2 = *(const bf16x8*)(wihl + (sbs[2] + m) * 64 + wro);
      bf16x8 w3 = *(const bf16x8*)(wihl + (sbs[3] + m) * 64 + wro);
      bf16x8 w4 = *(const bf16x8*)(wihl + (sbs[4] + m) * 64 + wro);
      bf16x8 w5 = *(const bf16x8*)(wihl + (sbs[5] + m) * 64 + wro);
      acc0 = __builtin_amdgcn_mfma_f32_16x16x32_bf16(w0, xf, z4, 0, 0, 0);
      acc1 = __builtin_amdgcn_mfma_f32_16x16x32_bf16(w1, xf, z4, 0, 0, 0);
      acc2 = __builtin_amdgcn_mfma_f32_16x16x32_bf16(w2, xf, z4, 0, 0, 0);
      acc3 = __builtin_amdgcn_mfma_f32_16x16x32_bf16(w3, xf, z4, 0, 0, 0);
      acc4 = __builtin_amdgcn_mfma_f32_16x16x32_bf16(w4, xf, z4, 0, 0, 0);
      acc5 = __builtin_amdgcn_mfma_f32_16x16x32_bf16(w5, xf, z4, 0, 0, 0);
    }
    __syncthreads();
  }

  // ---- output: out[b] = sum_j h[b][j] * w_dense[j] + b_dense[0] ----
  if (tid < 64) {
    const char* hb = zb + (TT & 1) * ZBUF;           // TT=365 -> buffer 1
    int row = tid >> 3, seg = tid & 7;
    float sum = 0.0f;
    #pragma unroll
    for (int jj = 0; jj < 32; ++jj) {
      int j = seg * 32 + jj;
      unsigned short hu = *(const unsigned short*)(hb + row * 512 + ((j * 2) ^ (row << 4)));
      sum += bf2f(hu) * w_dense[j];
    }
    sum += __shfl_xor(sum, 1, 64);
    sum += __shfl_xor(sum, 2, 64);
    sum += __shfl_xor(sum, 4, 64);
    if (seg == 0) out[b0 + row] = sum + b_dense[0];
  }
}

extern "C" void kernel_launch(void* const* d_in, const int* in_sizes, int n_in,
                              void* d_out, int out_size, void* d_ws, size_t ws_size,
                              hipStream_t stream) {
  (void)in_sizes; (void)n_in; (void)out_size; (void)ws_size;
  const float* x_dd = (const float*)d_in[0];
  const float* x_s  = (const float*)d_in[1];
  const float* wih  = (const float*)d_in[2];
  const float* whh  = (const float*)d_in[3];
  const float* bias = (const float*)d_in[4];
  const float* w_in = (const float*)d_in[5];
  const float* b_in = (const float*)d_in[6];
  const float* w_d  = (const float*)d_in[7];
  const float* b_d  = (const float*)d_in[8];
  float* out = (float*)d_out;
  unsigned char* ws = (unsigned char*)d_ws;

  unsigned short* whh_bf = (unsigned short*)ws;
  unsigned short* wih_bf = (unsigned short*)(ws + WS_WIH);
  float*          bias_s = (float*)(ws + WS_BIAS);

  prep_kernel<<<128, 256, 0, stream>>>(whh, wih, bias, whh_bf, wih_bf, bias_s);
  ealstm_kernel<<<BTOT / 8, BLOCK, 0, stream>>>(
      x_dd, x_s, w_in, b_in, w_d, b_d, whh_bf, wih_bf, bias_s, out);
}

// Round 11
// 609.946 us; speedup vs baseline: 1.3817x; 1.0235x over previous
//
#include <hip/hip_runtime.h>

#define TT   365
#define BTOT 2048
#define DIN  32
#define SIN  27
#define HD   256
#define G3   768
#define BLOCK 512
#define ZBUF 4096
#define WIHL_OFF 8192
#define WHH7_OFF (WIHL_OFF + G3*64)   // 57344
#define SMEM_SZ  (WHH7_OFF + G3*64)   // 106496
#define L2E  1.442695040888963f

// ws layout (all written by prep): whh_bf16 | wih_bf16 | bias_scaled_f32
#define WS_WIH  (G3*HD*2)            // 393216
#define WS_BIAS (WS_WIH + G3*DIN*2)  // 442368

typedef float  f32x4  __attribute__((ext_vector_type(4)));
typedef short  bf16x8 __attribute__((ext_vector_type(8)));
typedef unsigned int u32x2 __attribute__((ext_vector_type(2)));
typedef unsigned int u32x4 __attribute__((ext_vector_type(4)));

__device__ __forceinline__ unsigned short f2bf(float f) {
  unsigned u = __builtin_bit_cast(unsigned, f);
  u += 0x7fffu + ((u >> 16) & 1u);          // RNE to bf16
  return (unsigned short)(u >> 16);
}
__device__ __forceinline__ float bf2f(unsigned short u) {
  unsigned v = ((unsigned)u) << 16;
  return __builtin_bit_cast(float, v);
}
__device__ __forceinline__ bf16x8 cvt8(f32x4 a, f32x4 c) {
  unsigned c0, c1, c2, c3;
  asm("v_cvt_pk_bf16_f32 %0, %1, %2" : "=v"(c0) : "v"(a[0]), "v"(a[1]));
  asm("v_cvt_pk_bf16_f32 %0, %1, %2" : "=v"(c1) : "v"(a[2]), "v"(a[3]));
  asm("v_cvt_pk_bf16_f32 %0, %1, %2" : "=v"(c2) : "v"(c[0]), "v"(c[1]));
  asm("v_cvt_pk_bf16_f32 %0, %1, %2" : "=v"(c3) : "v"(c[2]), "v"(c[3]));
  u32x4 u = u32x4{c0, c1, c2, c3};
  return __builtin_bit_cast(bf16x8, u);
}

// prep: bf16-quantize weights with log2e folded (f,o rows x L2E; g rows x 2*L2E),
// and prescale bias the same way.
__global__ void prep_kernel(const float* __restrict__ whh, const float* __restrict__ wih,
                            const float* __restrict__ bias,
                            unsigned short* __restrict__ whh_bf,
                            unsigned short* __restrict__ wih_bf,
                            float* __restrict__ bias_s) {
  int stride = gridDim.x * blockDim.x;
  int i0 = blockIdx.x * blockDim.x + threadIdx.x;
  for (int i = i0; i < G3 * HD; i += stride) {
    int row = i >> 8;
    float s = (row >= HD && row < 2 * HD) ? 2.0f * L2E : L2E;
    whh_bf[i] = f2bf(whh[i] * s);
  }
  for (int i = i0; i < G3 * DIN; i += stride) {
    int row = i >> 5;
    float s = (row >= HD && row < 2 * HD) ? 2.0f * L2E : L2E;
    wih_bf[i] = f2bf(wih[i] * s);
  }
  for (int i = i0; i < G3; i += stride) {
    float s = (i >= HD && i < 2 * HD) ? 2.0f * L2E : L2E;
    bias_s[i] = bias[i] * s;
  }
}

// Persistent block per 8 batch rows, transposed orientation:
// gates^T(768 x 8) = Whh~ (A, gate-rows) x h^T (B, cols=batch, LDS).
// Whh kk=0..6 pinned in registers (168 VGPR, asm opaque barrier); kk=7 + Wih
// in LDS (rotation-swizzled). x in per-lane registers: x(t+1) loads issued at
// the TOP of step t (covered by the whole recurrent MFMA chain), consumed in
// the tail by the t+1 x-projection, which sits between EW1 and EW2 so the
// scheduler can interleave its MFMAs with the transcendental chains.
__global__ void __launch_bounds__(BLOCK, 2)
ealstm_kernel(const float* __restrict__ x_dd, const float* __restrict__ x_s,
              const float* __restrict__ w_in, const float* __restrict__ b_in,
              const float* __restrict__ w_dense, const float* __restrict__ b_dense,
              const unsigned short* __restrict__ whh_bf,
              const unsigned short* __restrict__ wih_bf,
              const float* __restrict__ bias_s,
              float* __restrict__ out) {
  __shared__ __attribute__((aligned(16))) char sm[SMEM_SZ];   // 104 KB
  char* zb    = sm;             // 2 x 4096: h double buffer
  char* wihl  = sm + WIHL_OFF;  // Wih~ rows, 64B stride, rot-swizzled octets
  char* whh7l = sm + WHH7_OFF;  // Whh~ kk=7 octets, same layout

  const int tid  = threadIdx.x;
  const int b0   = blockIdx.x * 8;
  const int w    = tid >> 6;
  const int lane = tid & 63;
  const int m    = lane & 15;
  const int q    = lane >> 4;
  const int b    = m & 7;
  const int half = m >> 3;

  // stage Wih~ and Whh~[kk=7] into LDS: row r octet qq at r*64 + rot(qq,r)
  for (int i = tid; i < G3 * 4; i += BLOCK) {
    int row = i >> 2, qq = i & 3;
    int rot = ((qq + ((row >> 1) & 3)) & 3) << 4;
    *(bf16x8*)(wihl + row * 64 + rot)  = *(const bf16x8*)(wih_bf + row * DIN + qq * 8);
    *(bf16x8*)(whh7l + row * 64 + rot) =
        *(const bf16x8*)(whh_bf + (size_t)row * HD + 7 * 32 + qq * 8);
  }
  // zero h of buffer 0
  if (tid < 256) *(f32x4*)(zb + tid * 16) = f32x4{0.f, 0.f, 0.f, 0.f};

  // per-lane x source: 8 consecutive f32 of x_dd[t][b0+b][q*8..]
  const float* xp = x_dd + ((size_t)(b0 + b)) * DIN + q * 8;
  f32x4 xa = *(const f32x4*)xp;
  f32x4 xc = *(const f32x4*)(xp + 4);
  xp += (size_t)BTOT * DIN;                 // -> t=1

  // Whh~ A-fragments kk=0..6 in registers (forced residency via asm barrier)
  const int sb0 = w * 16;
  int sbs[6];
  bf16x8 wr[6][7];
  #pragma unroll
  for (int s = 0; s < 6; ++s) {
    int sbase = sb0 + (s >= 3 ? 128 : 0) + (s % 3) * 256;
    sbs[s] = sbase;
    const unsigned short* wp = whh_bf + (size_t)(sbase + m) * HD + q * 8;
    #pragma unroll
    for (int kk = 0; kk < 7; ++kk) wr[s][kk] = *(const bf16x8*)(wp + kk * 32);
  }
  #pragma unroll
  for (int s = 0; s < 6; ++s)
    #pragma unroll
    for (int kk = 0; kk < 7; ++kk)
      asm volatile("" : "+v"(wr[s][kk]));   // opaque: no remat, must stay resident

  // per-lane (j, b) mapping: j = j0 + r, batch = b
  const int j0 = sb0 + half * 128 + q * 4;
  float cst[4], ig[4];
  #pragma unroll
  for (int r = 0; r < 4; ++r) {
    int j = j0 + r;
    float a = b_in[j];
    const float* xr = x_s + (size_t)(b0 + b) * SIN;
    const float* wn = w_in + (size_t)j * SIN;
    #pragma unroll
    for (int ss = 0; ss < SIN; ++ss) a += xr[ss] * wn[ss];
    ig[r] = __builtin_amdgcn_rcpf(1.0f + __builtin_amdgcn_exp2f(-a * L2E));
    cst[r] = 0.0f;
  }

  const int swz = b << 4;
  const int wro = ((q + ((m >> 1) & 3)) & 3) << 4;              // LDS weight read rot
  const int hrb = b * 512;
  const int hq  = q * 16;
  const int hw  = b * 512 + ((j0 * 2) ^ swz);                   // h write (rel. buffer)
  const float* bfp = bias_s + j0;
  const float* bgp = bias_s + 256 + j0;
  const float* bop = bias_s + 512 + j0;

  const f32x4 z4 = f32x4{0.f, 0.f, 0.f, 0.f};
  __syncthreads();

  f32x4 acc0, acc1, acc2, acc3, acc4, acc5;
  {   // x-projection for t=0 (C=0; bias added in EW)
    bf16x8 xf = cvt8(xa, xc);
    bf16x8 w0 = *(const bf16x8*)(wihl + (sbs[0] + m) * 64 + wro);
    bf16x8 w1 = *(const bf16x8*)(wihl + (sbs[1] + m) * 64 + wro);
    bf16x8 w2 = *(const bf16x8*)(wihl + (sbs[2] + m) * 64 + wro);
    bf16x8 w3 = *(const bf16x8*)(wihl + (sbs[3] + m) * 64 + wro);
    bf16x8 w4 = *(const bf16x8*)(wihl + (sbs[4] + m) * 64 + wro);
    bf16x8 w5 = *(const bf16x8*)(wihl + (sbs[5] + m) * 64 + wro);
    acc0 = __builtin_amdgcn_mfma_f32_16x16x32_bf16(w0, xf, z4, 0, 0, 0);
    acc1 = __builtin_amdgcn_mfma_f32_16x16x32_bf16(w1, xf, z4, 0, 0, 0);
    acc2 = __builtin_amdgcn_mfma_f32_16x16x32_bf16(w2, xf, z4, 0, 0, 0);
    acc3 = __builtin_amdgcn_mfma_f32_16x16x32_bf16(w3, xf, z4, 0, 0, 0);
    acc4 = __builtin_amdgcn_mfma_f32_16x16x32_bf16(w4, xf, z4, 0, 0, 0);
    acc5 = __builtin_amdgcn_mfma_f32_16x16x32_bf16(w5, xf, z4, 0, 0, 0);
  }

  for (int t = 0; t < TT; ++t) {
    char* zc = zb + (t & 1) * ZBUF;
    char* zn = zb + ((t + 1) & 1) * ZBUF;
    const bool more = (t + 1 < TT);

    // ---- issue x(t+1) loads FIRST: covered by the full recurrent chain ----
    if (more) {
      xa = *(const f32x4*)xp;
      xc = *(const f32x4*)(xp + 4);
      xp += (size_t)BTOT * DIN;
    }
    f32x4 bf4 = *(const f32x4*)bfp;                  // L1-hit (prescaled bias)
    f32x4 bg4 = *(const f32x4*)bgp;
    f32x4 bo4 = *(const f32x4*)bop;

    // ---- recurrent MFMA chain: kk=0..6 from registers, kk=7 from LDS ----
    #pragma unroll
    for (int kk = 0; kk < 7; ++kk) {
      bf16x8 hf = *(const bf16x8*)(zc + hrb + ((kk * 64 + hq) ^ swz));
      acc0 = __builtin_amdgcn_mfma_f32_16x16x32_bf16(wr[0][kk], hf, acc0, 0, 0, 0);
      acc1 = __builtin_amdgcn_mfma_f32_16x16x32_bf16(wr[1][kk], hf, acc1, 0, 0, 0);
      acc2 = __builtin_amdgcn_mfma_f32_16x16x32_bf16(wr[2][kk], hf, acc2, 0, 0, 0);
      acc3 = __builtin_amdgcn_mfma_f32_16x16x32_bf16(wr[3][kk], hf, acc3, 0, 0, 0);
      acc4 = __builtin_amdgcn_mfma_f32_16x16x32_bf16(wr[4][kk], hf, acc4, 0, 0, 0);
      acc5 = __builtin_amdgcn_mfma_f32_16x16x32_bf16(wr[5][kk], hf, acc5, 0, 0, 0);
    }
    {   // kk = 7 from LDS
      bf16x8 hf = *(const bf16x8*)(zc + hrb + ((7 * 64 + hq) ^ swz));
      bf16x8 u0 = *(const bf16x8*)(whh7l + (sbs[0] + m) * 64 + wro);
      bf16x8 u1 = *(const bf16x8*)(whh7l + (sbs[1] + m) * 64 + wro);
      bf16x8 u2 = *(const bf16x8*)(whh7l + (sbs[2] + m) * 64 + wro);
      bf16x8 u3 = *(const bf16x8*)(whh7l + (sbs[3] + m) * 64 + wro);
      bf16x8 u4 = *(const bf16x8*)(whh7l + (sbs[4] + m) * 64 + wro);
      bf16x8 u5 = *(const bf16x8*)(whh7l + (sbs[5] + m) * 64 + wro);
      acc0 = __builtin_amdgcn_mfma_f32_16x16x32_bf16(u0, hf, acc0, 0, 0, 0);
      acc1 = __builtin_amdgcn_mfma_f32_16x16x32_bf16(u1, hf, acc1, 0, 0, 0);
      acc2 = __builtin_amdgcn_mfma_f32_16x16x32_bf16(u2, hf, acc2, 0, 0, 0);
      acc3 = __builtin_amdgcn_mfma_f32_16x16x32_bf16(u3, hf, acc3, 0, 0, 0);
      acc4 = __builtin_amdgcn_mfma_f32_16x16x32_bf16(u4, hf, acc4, 0, 0, 0);
      acc5 = __builtin_amdgcn_mfma_f32_16x16x32_bf16(u5, hf, acc5, 0, 0, 0);
    }

    // ---- EW1: f,g,c-update; also extract po so all accs die here ----
    float po[4];
    #pragma unroll
    for (int r = 0; r < 4; ++r) {
      float pf = (half ? acc3[r] : acc0[r]) + bf4[r];
      float pg = (half ? acc4[r] : acc1[r]) + bg4[r];
      po[r]    = (half ? acc5[r] : acc2[r]) + bo4[r];
      float fg = __builtin_amdgcn_rcpf(1.0f + __builtin_amdgcn_exp2f(-pf));
      float gg = 1.0f - 2.0f * __builtin_amdgcn_rcpf(1.0f + __builtin_amdgcn_exp2f(pg));
      cst[r] = fg * cst[r] + ig[r] * gg;
    }

    // ---- x-projection for t+1 (independent of EW; interleaves with trans) ----
    if (more) {
      bf16x8 xf = cvt8(xa, xc);
      bf16x8 w0 = *(const bf16x8*)(wihl + (sbs[0] + m) * 64 + wro);
      bf16x8 w1 = *(const bf16x8*)(wihl + (sbs[1] + m) * 64 + wro);
      bf16x8 w2 = *(const bf16x8*)(wihl + (sbs[2] + m) * 64 + wro);
      bf16x8 w3 = *(const bf16x8*)(wihl + (sbs[3] + m) * 64 + wro);
      bf16x8 w4 = *(const bf16x8*)(wihl + (sbs[4] + m) * 64 + wro);
      bf16x8 w5 = *(const bf16x8*)(wihl + (sbs[5] + m) * 64 + wro);
      acc0 = __builtin_amdgcn_mfma_f32_16x16x32_bf16(w0, xf, z4, 0, 0, 0);
      acc1 = __builtin_amdgcn_mfma_f32_16x16x32_bf16(w1, xf, z4, 0, 0, 0);
      acc2 = __builtin_amdgcn_mfma_f32_16x16x32_bf16(w2, xf, z4, 0, 0, 0);
      acc3 = __builtin_amdgcn_mfma_f32_16x16x32_bf16(w3, xf, z4, 0, 0, 0);
      acc4 = __builtin_amdgcn_mfma_f32_16x16x32_bf16(w4, xf, z4, 0, 0, 0);
      acc5 = __builtin_amdgcn_mfma_f32_16x16x32_bf16(w5, xf, z4, 0, 0, 0);
    }

    // ---- EW2: o, tanh(c), h pack/write ----
    float h0, h1, h2, h3;
    #pragma unroll
    for (int r = 0; r < 4; ++r) {
      float og = __builtin_amdgcn_rcpf(1.0f + __builtin_amdgcn_exp2f(-po[r]));
      float th = 1.0f - 2.0f * __builtin_amdgcn_rcpf(1.0f + __builtin_amdgcn_exp2f(cst[r] * (2.0f * L2E)));
      float hv = og * th;
      if (r == 0) h0 = hv; else if (r == 1) h1 = hv; else if (r == 2) h2 = hv; else h3 = hv;
    }
    unsigned pk0, pk1;
    asm("v_cvt_pk_bf16_f32 %0, %1, %2" : "=v"(pk0) : "v"(h0), "v"(h1));
    asm("v_cvt_pk_bf16_f32 %0, %1, %2" : "=v"(pk1) : "v"(h2), "v"(h3));
    u32x2 pk = u32x2{pk0, pk1};
    *(u32x2*)(zn + hw) = pk;                         // one ds_write_b64

    __syncthreads();
  }

  // ---- output: out[b] = sum_j h[b][j] * w_dense[j] + b_dense[0] ----
  if (tid < 64) {
    const char* hb = zb + (TT & 1) * ZBUF;           // TT=365 -> buffer 1
    int row = tid >> 3, seg = tid & 7;
    float sum = 0.0f;
    #pragma unroll
    for (int jj = 0; jj < 32; ++jj) {
      int j = seg * 32 + jj;
      unsigned short hu = *(const unsigned short*)(hb + row * 512 + ((j * 2) ^ (row << 4)));
      sum += bf2f(hu) * w_dense[j];
    }
    sum += __shfl_xor(sum, 1, 64);
    sum += __shfl_xor(sum, 2, 64);
    sum += __shfl_xor(sum, 4, 64);
    if (seg == 0) out[b0 + row] = sum + b_dense[0];
  }
}

extern "C" void kernel_launch(void* const* d_in, const int* in_sizes, int n_in,
                              void* d_out, int out_size, void* d_ws, size_t ws_size,
                              hipStream_t stream) {
  (void)in_sizes; (void)n_in; (void)out_size; (void)ws_size;
  const float* x_dd = (const float*)d_in[0];
  const float* x_s  = (const float*)d_in[1];
  const float* wih  = (const float*)d_in[2];
  const float* whh  = (const float*)d_in[3];
  const float* bias = (const float*)d_in[4];
  const float* w_in = (const float*)d_in[5];
  const float* b_in = (const float*)d_in[6];
  const float* w_d  = (const float*)d_in[7];
  const float* b_d  = (const float*)d_in[8];
  float* out = (float*)d_out;
  unsigned char* ws = (unsigned char*)d_ws;

  unsigned short* whh_bf = (unsigned short*)ws;
  unsigned short* wih_bf = (unsigned short*)(ws + WS_WIH);
  float*          bias_s = (float*)(ws + WS_BIAS);

  prep_kernel<<<128, 256, 0, stream>>>(whh, wih, bias, whh_bf, wih_bf, bias_s);
  ealstm_kernel<<<BTOT / 8, BLOCK, 0, stream>>>(
      x_dd, x_s, w_in, b_in, w_d, b_d, whh_bf, wih_bf, bias_s, out);
}

// Round 12
// 592.335 us; speedup vs baseline: 1.4228x; 1.0297x over previous
//
#include <hip/hip_runtime.h>

#define TT   365
#define BTOT 2048
#define DIN  32
#define SIN  27
#define HD   256
#define G3   768
#define BLOCK 512
#define ZBUF 4608
#define XOFF 4096
#define WHH6_OFF 9216
#define WHH7_OFF (WHH6_OFF + G3*64)   // 58368
#define SMEM_SZ  (WHH7_OFF + G3*64)   // 107520
#define L2E  1.442695040888963f

// ws layout (all written by prep): whh_bf16 | wih_bf16 | bias_scaled_f32
#define WS_WIH  (G3*HD*2)            // 393216
#define WS_BIAS (WS_WIH + G3*DIN*2)  // 442368

typedef float  f32x4  __attribute__((ext_vector_type(4)));
typedef short  bf16x8 __attribute__((ext_vector_type(8)));
typedef unsigned int u32x2 __attribute__((ext_vector_type(2)));

__device__ __forceinline__ unsigned short f2bf(float f) {
  unsigned u = __builtin_bit_cast(unsigned, f);
  u += 0x7fffu + ((u >> 16) & 1u);          // RNE to bf16
  return (unsigned short)(u >> 16);
}
__device__ __forceinline__ float bf2f(unsigned short u) {
  unsigned v = ((unsigned)u) << 16;
  return __builtin_bit_cast(float, v);
}

// prep: bf16-quantize weights with log2e folded (f,o rows x L2E; g rows x 2*L2E),
// and prescale bias the same way.
__global__ void prep_kernel(const float* __restrict__ whh, const float* __restrict__ wih,
                            const float* __restrict__ bias,
                            unsigned short* __restrict__ whh_bf,
                            unsigned short* __restrict__ wih_bf,
                            float* __restrict__ bias_s) {
  int stride = gridDim.x * blockDim.x;
  int i0 = blockIdx.x * blockDim.x + threadIdx.x;
  for (int i = i0; i < G3 * HD; i += stride) {
    int row = i >> 8;
    float s = (row >= HD && row < 2 * HD) ? 2.0f * L2E : L2E;
    whh_bf[i] = f2bf(whh[i] * s);
  }
  for (int i = i0; i < G3 * DIN; i += stride) {
    int row = i >> 5;
    float s = (row >= HD && row < 2 * HD) ? 2.0f * L2E : L2E;
    wih_bf[i] = f2bf(wih[i] * s);
  }
  for (int i = i0; i < G3; i += stride) {
    float s = (i >= HD && i < 2 * HD) ? 2.0f * L2E : L2E;
    bias_s[i] = bias[i] * s;
  }
}

// Persistent block per 8 batch rows, transposed orientation:
// gates^T(768 x 8) = Whh~ (A, gate-rows) x h^T (B, cols=batch, LDS).
// PINNED in registers (168, asm opaque barrier): Wih frags (24) + Whh kk=0..5
// (144). Whh kk=6,7 in LDS slabs (rotation-swizzled), read mid-chain where
// the LDS pipe has slack. Post-barrier xproj is read-free (1 x-read only) so
// the MFMA pipe starts immediately and covers the h-read latency.
__global__ void __launch_bounds__(BLOCK, 2)
ealstm_kernel(const float* __restrict__ x_dd, const float* __restrict__ x_s,
              const float* __restrict__ w_in, const float* __restrict__ b_in,
              const float* __restrict__ w_dense, const float* __restrict__ b_dense,
              const unsigned short* __restrict__ whh_bf,
              const unsigned short* __restrict__ wih_bf,
              const float* __restrict__ bias_s,
              float* __restrict__ out) {
  __shared__ __attribute__((aligned(16))) char sm[SMEM_SZ];   // 105 KB
  char* zb    = sm;             // 2 x 4608: h (4096) + x (512) per buffer
  char* whh6l = sm + WHH6_OFF;  // Whh~ kk=6 octets, 64B row stride, rot-swizzled
  char* whh7l = sm + WHH7_OFF;  // Whh~ kk=7 octets, same layout

  const int tid  = threadIdx.x;
  const int b0   = blockIdx.x * 8;
  const int w    = tid >> 6;
  const int lane = tid & 63;
  const int m    = lane & 15;
  const int q    = lane >> 4;
  const int b    = m & 7;
  const int half = m >> 3;

  // stage Whh~[kk=6] and Whh~[kk=7] into LDS: row r octet qq at r*64 + rot(qq,r)
  for (int i = tid; i < G3 * 4; i += BLOCK) {
    int row = i >> 2, qq = i & 3;
    int rot = ((qq + ((row >> 1) & 3)) & 3) << 4;
    *(bf16x8*)(whh6l + row * 64 + rot) =
        *(const bf16x8*)(whh_bf + (size_t)row * HD + 6 * 32 + qq * 8);
    *(bf16x8*)(whh7l + row * 64 + rot) =
        *(const bf16x8*)(whh_bf + (size_t)row * HD + 7 * 32 + qq * 8);
  }
  // zero h of buffer 0
  if (tid < 256) *(f32x4*)(zb + tid * 16) = f32x4{0.f, 0.f, 0.f, 0.f};

  // x staging slot (rotation-swizzled octets): row xr_, elem xd
  const bool xthr = tid < 256;
  const int xr_ = (tid >> 5) & 7, xd = tid & 31;
  const int xso = XOFF + xr_ * 64 + ((((xd >> 3) + (xr_ >> 1)) & 3) << 4) + (xd & 7) * 2;
  const float* xq = x_dd + (size_t)(b0 + xr_) * DIN + xd;
  if (xthr) *(unsigned short*)(zb + xso) = f2bf(xq[0]);   // x(0) -> buf0
  xq += (size_t)BTOT * DIN;                               // -> x(1)

  // Pinned register weights: Whh kk=0..5 (144) + Wih frags (24)
  const int sb0 = w * 16;
  int sbs[6];
  bf16x8 wr[6][6];
  bf16x8 wx[6];
  #pragma unroll
  for (int s = 0; s < 6; ++s) {
    int sbase = sb0 + (s >= 3 ? 128 : 0) + (s % 3) * 256;
    sbs[s] = sbase;
    const unsigned short* wp = whh_bf + (size_t)(sbase + m) * HD + q * 8;
    #pragma unroll
    for (int kk = 0; kk < 6; ++kk) wr[s][kk] = *(const bf16x8*)(wp + kk * 32);
    wx[s] = *(const bf16x8*)(wih_bf + (size_t)(sbase + m) * DIN + q * 8);
  }
  #pragma unroll
  for (int s = 0; s < 6; ++s) {
    #pragma unroll
    for (int kk = 0; kk < 6; ++kk)
      asm volatile("" : "+v"(wr[s][kk]));   // opaque: no remat, must stay resident
    asm volatile("" : "+v"(wx[s]));
  }

  // per-lane (j, b) mapping: j = j0 + r, batch = b
  const int j0 = sb0 + half * 128 + q * 4;
  float cst[4], ig[4];
  #pragma unroll
  for (int r = 0; r < 4; ++r) {
    int j = j0 + r;
    float a = b_in[j];
    const float* xr = x_s + (size_t)(b0 + b) * SIN;
    const float* wn = w_in + (size_t)j * SIN;
    #pragma unroll
    for (int ss = 0; ss < SIN; ++ss) a += xr[ss] * wn[ss];
    ig[r] = __builtin_amdgcn_rcpf(1.0f + __builtin_amdgcn_exp2f(-a * L2E));
    cst[r] = 0.0f;
  }

  const int swz = b << 4;
  const int wro = ((q + ((m >> 1) & 3)) & 3) << 4;              // LDS weight read rot
  const int xrd = XOFF + b * 64 + (((q + (b >> 1)) & 3) << 4);  // x B-frag read
  const int hrb = b * 512;
  const int hq  = q * 16;
  const int hw  = b * 512 + ((j0 * 2) ^ swz);                   // h write (rel. buffer)
  const float* bfp = bias_s + j0;
  const float* bgp = bias_s + 256 + j0;
  const float* bop = bias_s + 512 + j0;

  const f32x4 z4 = f32x4{0.f, 0.f, 0.f, 0.f};
  __syncthreads();

  for (int t = 0; t < TT; ++t) {
    char* zc = zb + (t & 1) * ZBUF;
    char* zn = zb + ((t + 1) & 1) * ZBUF;

    float xv = 0.0f;
    if (xthr && t + 1 < TT) xv = xq[0];
    f32x4 bf4 = *(const f32x4*)bfp;                  // L1-hit (prescaled bias)
    f32x4 bg4 = *(const f32x4*)bgp;
    f32x4 bo4 = *(const f32x4*)bop;

    // ---- xproj first: pinned Wih, only ONE LDS read (x) before 6 MFMAs ----
    bf16x8 xf = *(const bf16x8*)(zc + xrd);
    f32x4 acc0, acc1, acc2, acc3, acc4, acc5;
    acc0 = __builtin_amdgcn_mfma_f32_16x16x32_bf16(wx[0], xf, z4, 0, 0, 0);
    acc1 = __builtin_amdgcn_mfma_f32_16x16x32_bf16(wx[1], xf, z4, 0, 0, 0);
    acc2 = __builtin_amdgcn_mfma_f32_16x16x32_bf16(wx[2], xf, z4, 0, 0, 0);
    acc3 = __builtin_amdgcn_mfma_f32_16x16x32_bf16(wx[3], xf, z4, 0, 0, 0);
    acc4 = __builtin_amdgcn_mfma_f32_16x16x32_bf16(wx[4], xf, z4, 0, 0, 0);
    acc5 = __builtin_amdgcn_mfma_f32_16x16x32_bf16(wx[5], xf, z4, 0, 0, 0);

    // ---- recurrent chain: kk=0..5 from registers ----
    #pragma unroll
    for (int kk = 0; kk < 6; ++kk) {
      bf16x8 hf = *(const bf16x8*)(zc + hrb + ((kk * 64 + hq) ^ swz));
      acc0 = __builtin_amdgcn_mfma_f32_16x16x32_bf16(wr[0][kk], hf, acc0, 0, 0, 0);
      acc1 = __builtin_amdgcn_mfma_f32_16x16x32_bf16(wr[1][kk], hf, acc1, 0, 0, 0);
      acc2 = __builtin_amdgcn_mfma_f32_16x16x32_bf16(wr[2][kk], hf, acc2, 0, 0, 0);
      acc3 = __builtin_amdgcn_mfma_f32_16x16x32_bf16(wr[3][kk], hf, acc3, 0, 0, 0);
      acc4 = __builtin_amdgcn_mfma_f32_16x16x32_bf16(wr[4][kk], hf, acc4, 0, 0, 0);
      acc5 = __builtin_amdgcn_mfma_f32_16x16x32_bf16(wr[5][kk], hf, acc5, 0, 0, 0);
    }
    {   // kk = 6 from LDS
      bf16x8 hf = *(const bf16x8*)(zc + hrb + ((6 * 64 + hq) ^ swz));
      bf16x8 u0 = *(const bf16x8*)(whh6l + (sbs[0] + m) * 64 + wro);
      bf16x8 u1 = *(const bf16x8*)(whh6l + (sbs[1] + m) * 64 + wro);
      bf16x8 u2 = *(const bf16x8*)(whh6l + (sbs[2] + m) * 64 + wro);
      bf16x8 u3 = *(const bf16x8*)(whh6l + (sbs[3] + m) * 64 + wro);
      bf16x8 u4 = *(const bf16x8*)(whh6l + (sbs[4] + m) * 64 + wro);
      bf16x8 u5 = *(const bf16x8*)(whh6l + (sbs[5] + m) * 64 + wro);
      acc0 = __builtin_amdgcn_mfma_f32_16x16x32_bf16(u0, hf, acc0, 0, 0, 0);
      acc1 = __builtin_amdgcn_mfma_f32_16x16x32_bf16(u1, hf, acc1, 0, 0, 0);
      acc2 = __builtin_amdgcn_mfma_f32_16x16x32_bf16(u2, hf, acc2, 0, 0, 0);
      acc3 = __builtin_amdgcn_mfma_f32_16x16x32_bf16(u3, hf, acc3, 0, 0, 0);
      acc4 = __builtin_amdgcn_mfma_f32_16x16x32_bf16(u4, hf, acc4, 0, 0, 0);
      acc5 = __builtin_amdgcn_mfma_f32_16x16x32_bf16(u5, hf, acc5, 0, 0, 0);
    }
    {   // kk = 7 from LDS
      bf16x8 hf = *(const bf16x8*)(zc + hrb + ((7 * 64 + hq) ^ swz));
      bf16x8 u0 = *(const bf16x8*)(whh7l + (sbs[0] + m) * 64 + wro);
      bf16x8 u1 = *(const bf16x8*)(whh7l + (sbs[1] + m) * 64 + wro);
      bf16x8 u2 = *(const bf16x8*)(whh7l + (sbs[2] + m) * 64 + wro);
      bf16x8 u3 = *(const bf16x8*)(whh7l + (sbs[3] + m) * 64 + wro);
      bf16x8 u4 = *(const bf16x8*)(whh7l + (sbs[4] + m) * 64 + wro);
      bf16x8 u5 = *(const bf16x8*)(whh7l + (sbs[5] + m) * 64 + wro);
      acc0 = __builtin_amdgcn_mfma_f32_16x16x32_bf16(u0, hf, acc0, 0, 0, 0);
      acc1 = __builtin_amdgcn_mfma_f32_16x16x32_bf16(u1, hf, acc1, 0, 0, 0);
      acc2 = __builtin_amdgcn_mfma_f32_16x16x32_bf16(u2, hf, acc2, 0, 0, 0);
      acc3 = __builtin_amdgcn_mfma_f32_16x16x32_bf16(u3, hf, acc3, 0, 0, 0);
      acc4 = __builtin_amdgcn_mfma_f32_16x16x32_bf16(u4, hf, acc4, 0, 0, 0);
      acc5 = __builtin_amdgcn_mfma_f32_16x16x32_bf16(u5, hf, acc5, 0, 0, 0);
    }

    // ---- elementwise (pre-activations prescaled by log2e; 2*log2e for g) ----
    float h0, h1, h2, h3;
    #pragma unroll
    for (int r = 0; r < 4; ++r) {
      float pf = (half ? acc3[r] : acc0[r]) + bf4[r];
      float pg = (half ? acc4[r] : acc1[r]) + bg4[r];
      float po = (half ? acc5[r] : acc2[r]) + bo4[r];
      float fg = __builtin_amdgcn_rcpf(1.0f + __builtin_amdgcn_exp2f(-pf));
      float gg = 1.0f - 2.0f * __builtin_amdgcn_rcpf(1.0f + __builtin_amdgcn_exp2f(pg));
      float og = __builtin_amdgcn_rcpf(1.0f + __builtin_amdgcn_exp2f(-po));
      float c  = fg * cst[r] + ig[r] * gg;
      cst[r] = c;
      float th = 1.0f - 2.0f * __builtin_amdgcn_rcpf(1.0f + __builtin_amdgcn_exp2f(c * (2.0f * L2E)));
      float hv = og * th;
      if (r == 0) h0 = hv; else if (r == 1) h1 = hv; else if (r == 2) h2 = hv; else h3 = hv;
    }
    unsigned pk0, pk1;
    asm("v_cvt_pk_bf16_f32 %0, %1, %2" : "=v"(pk0) : "v"(h0), "v"(h1));
    asm("v_cvt_pk_bf16_f32 %0, %1, %2" : "=v"(pk1) : "v"(h2), "v"(h3));
    u32x2 pk = u32x2{pk0, pk1};
    *(u32x2*)(zn + hw) = pk;                         // one ds_write_b64

    if (xthr && t + 1 < TT) {
      *(unsigned short*)(zn + xso) = f2bf(xv);
      xq += (size_t)BTOT * DIN;
    }
    __syncthreads();
  }

  // ---- output: out[b] = sum_j h[b][j] * w_dense[j] + b_dense[0] ----
  if (tid < 64) {
    const char* hb = zb + (TT & 1) * ZBUF;           // TT=365 -> buffer 1
    int row = tid >> 3, seg = tid & 7;
    float sum = 0.0f;
    #pragma unroll
    for (int jj = 0; jj < 32; ++jj) {
      int j = seg * 32 + jj;
      unsigned short hu = *(const unsigned short*)(hb + row * 512 + ((j * 2) ^ (row << 4)));
      sum += bf2f(hu) * w_dense[j];
    }
    sum += __shfl_xor(sum, 1, 64);
    sum += __shfl_xor(sum, 2, 64);
    sum += __shfl_xor(sum, 4, 64);
    if (seg == 0) out[b0 + row] = sum + b_dense[0];
  }
}

extern "C" void kernel_launch(void* const* d_in, const int* in_sizes, int n_in,
                              void* d_out, int out_size, void* d_ws, size_t ws_size,
                              hipStream_t stream) {
  (void)in_sizes; (void)n_in; (void)out_size; (void)ws_size;
  const float* x_dd = (const float*)d_in[0];
  const float* x_s  = (const float*)d_in[1];
  const float* wih  = (const float*)d_in[2];
  const float* whh  = (const float*)d_in[3];
  const float* bias = (const float*)d_in[4];
  const float* w_in = (const float*)d_in[5];
  const float* b_in = (const float*)d_in[6];
  const float* w_d  = (const float*)d_in[7];
  const float* b_d  = (const float*)d_in[8];
  float* out = (float*)d_out;
  unsigned char* ws = (unsigned char*)d_ws;

  unsigned short* whh_bf = (unsigned short*)ws;
  unsigned short* wih_bf = (unsigned short*)(ws + WS_WIH);
  float*          bias_s = (float*)(ws + WS_BIAS);

  prep_kernel<<<128, 256, 0, stream>>>(whh, wih, bias, whh_bf, wih_bf, bias_s);
  ealstm_kernel<<<BTOT / 8, BLOCK, 0, stream>>>(
      x_dd, x_s, w_in, b_in, w_d, b_d, whh_bf, wih_bf, bias_s, out);
}

// Round 13
// 518.469 us; speedup vs baseline: 1.6255x; 1.1425x over previous
//
#include <hip/hip_runtime.h>

#define TT   365
#define BTOT 2048
#define DIN  32
#define SIN  27
#define HD   256
#define G3   768
#define BLOCK 512
#define ZBUF 4096
#define WIHL_OFF 8192
#define WHH7_OFF (WIHL_OFF + G3*64)   // 57344
#define SMEM_SZ  (WHH7_OFF + G3*64)   // 106496
#define L2E  1.442695040888963f

// ws layout (all written by prep): whh_bf16 | wih_bf16 | bias_scaled_f32
#define WS_WIH  (G3*HD*2)            // 393216
#define WS_BIAS (WS_WIH + G3*DIN*2)  // 442368

typedef float  f32x4  __attribute__((ext_vector_type(4)));
typedef short  bf16x8 __attribute__((ext_vector_type(8)));
typedef unsigned int u32x2 __attribute__((ext_vector_type(2)));
typedef unsigned int u32x4 __attribute__((ext_vector_type(4)));

__device__ __forceinline__ unsigned short f2bf(float f) {
  unsigned u = __builtin_bit_cast(unsigned, f);
  u += 0x7fffu + ((u >> 16) & 1u);          // RNE to bf16
  return (unsigned short)(u >> 16);
}
__device__ __forceinline__ float bf2f(unsigned short u) {
  unsigned v = ((unsigned)u) << 16;
  return __builtin_bit_cast(float, v);
}
__device__ __forceinline__ bf16x8 cvt8(f32x4 a, f32x4 c) {
  unsigned c0, c1, c2, c3;
  asm("v_cvt_pk_bf16_f32 %0, %1, %2" : "=v"(c0) : "v"(a[0]), "v"(a[1]));
  asm("v_cvt_pk_bf16_f32 %0, %1, %2" : "=v"(c1) : "v"(a[2]), "v"(a[3]));
  asm("v_cvt_pk_bf16_f32 %0, %1, %2" : "=v"(c2) : "v"(c[0]), "v"(c[1]));
  asm("v_cvt_pk_bf16_f32 %0, %1, %2" : "=v"(c3) : "v"(c[2]), "v"(c[3]));
  u32x4 u = u32x4{c0, c1, c2, c3};
  return __builtin_bit_cast(bf16x8, u);
}

// prep: bf16-quantize weights with log2e folded (f,o rows x L2E; g rows x 2*L2E),
// and prescale bias the same way.
__global__ void prep_kernel(const float* __restrict__ whh, const float* __restrict__ wih,
                            const float* __restrict__ bias,
                            unsigned short* __restrict__ whh_bf,
                            unsigned short* __restrict__ wih_bf,
                            float* __restrict__ bias_s) {
  int stride = gridDim.x * blockDim.x;
  int i0 = blockIdx.x * blockDim.x + threadIdx.x;
  for (int i = i0; i < G3 * HD; i += stride) {
    int row = i >> 8;
    float s = (row >= HD && row < 2 * HD) ? 2.0f * L2E : L2E;
    whh_bf[i] = f2bf(whh[i] * s);
  }
  for (int i = i0; i < G3 * DIN; i += stride) {
    int row = i >> 5;
    float s = (row >= HD && row < 2 * HD) ? 2.0f * L2E : L2E;
    wih_bf[i] = f2bf(wih[i] * s);
  }
  for (int i = i0; i < G3; i += stride) {
    float s = (i >= HD && i < 2 * HD) ? 2.0f * L2E : L2E;
    bias_s[i] = bias[i] * s;
  }
}

// Persistent block per 8 batch rows, transposed orientation (r7 structure):
// gates^T(768 x 8) = Whh~ (A, gate-rows) x h^T (B, cols=batch, LDS).
// Whh kk=0..6 pinned in registers (168 VGPR, asm opaque barrier); kk=7 + Wih
// in LDS (rotation-swizzled). x lives in per-lane REGISTERS: x(t) converted at
// the step head (xproj stays FIRST, covering post-barrier LDS latency), x(t+1)
// global loads issued right after, covered by the whole recurrent chain.
// No x LDS staging: deletes divergent tid<256 path + ds_write + ds_read.
__global__ void __launch_bounds__(BLOCK, 2)
ealstm_kernel(const float* __restrict__ x_dd, const float* __restrict__ x_s,
              const float* __restrict__ w_in, const float* __restrict__ b_in,
              const float* __restrict__ w_dense, const float* __restrict__ b_dense,
              const unsigned short* __restrict__ whh_bf,
              const unsigned short* __restrict__ wih_bf,
              const float* __restrict__ bias_s,
              float* __restrict__ out) {
  __shared__ __attribute__((aligned(16))) char sm[SMEM_SZ];   // 104 KB
  char* zb    = sm;             // 2 x 4096: h double buffer
  char* wihl  = sm + WIHL_OFF;  // Wih~ rows, 64B stride, rot-swizzled octets
  char* whh7l = sm + WHH7_OFF;  // Whh~ kk=7 octets, same layout

  const int tid  = threadIdx.x;
  const int b0   = blockIdx.x * 8;
  const int w    = tid >> 6;
  const int lane = tid & 63;
  const int m    = lane & 15;
  const int q    = lane >> 4;
  const int b    = m & 7;
  const int half = m >> 3;

  // stage Wih~ and Whh~[kk=7] into LDS: row r octet qq at r*64 + rot(qq,r)
  for (int i = tid; i < G3 * 4; i += BLOCK) {
    int row = i >> 2, qq = i & 3;
    int rot = ((qq + ((row >> 1) & 3)) & 3) << 4;
    *(bf16x8*)(wihl + row * 64 + rot)  = *(const bf16x8*)(wih_bf + row * DIN + qq * 8);
    *(bf16x8*)(whh7l + row * 64 + rot) =
        *(const bf16x8*)(whh_bf + (size_t)row * HD + 7 * 32 + qq * 8);
  }
  // zero h of buffer 0
  if (tid < 256) *(f32x4*)(zb + tid * 16) = f32x4{0.f, 0.f, 0.f, 0.f};

  // per-lane x source: 8 consecutive f32 of x_dd[t][b0+b][q*8..]
  const float* xp = x_dd + ((size_t)(b0 + b)) * DIN + q * 8;
  f32x4 xa = *(const f32x4*)xp;
  f32x4 xc = *(const f32x4*)(xp + 4);
  xp += (size_t)BTOT * DIN;                 // -> t=1

  // Whh~ A-fragments kk=0..6 in registers (forced residency via asm barrier)
  const int sb0 = w * 16;
  int sbs[6];
  bf16x8 wr[6][7];
  #pragma unroll
  for (int s = 0; s < 6; ++s) {
    int sbase = sb0 + (s >= 3 ? 128 : 0) + (s % 3) * 256;
    sbs[s] = sbase;
    const unsigned short* wp = whh_bf + (size_t)(sbase + m) * HD + q * 8;
    #pragma unroll
    for (int kk = 0; kk < 7; ++kk) wr[s][kk] = *(const bf16x8*)(wp + kk * 32);
  }
  #pragma unroll
  for (int s = 0; s < 6; ++s)
    #pragma unroll
    for (int kk = 0; kk < 7; ++kk)
      asm volatile("" : "+v"(wr[s][kk]));   // opaque: no remat, must stay resident

  // per-lane (j, b) mapping: j = j0 + r, batch = b
  const int j0 = sb0 + half * 128 + q * 4;
  float cst[4], ig[4];
  #pragma unroll
  for (int r = 0; r < 4; ++r) {
    int j = j0 + r;
    float a = b_in[j];
    const float* xr = x_s + (size_t)(b0 + b) * SIN;
    const float* wn = w_in + (size_t)j * SIN;
    #pragma unroll
    for (int ss = 0; ss < SIN; ++ss) a += xr[ss] * wn[ss];
    ig[r] = __builtin_amdgcn_rcpf(1.0f + __builtin_amdgcn_exp2f(-a * L2E));
    cst[r] = 0.0f;
  }

  const int swz = b << 4;
  const int wro = ((q + ((m >> 1) & 3)) & 3) << 4;              // LDS weight read rot
  const int hrb = b * 512;
  const int hq  = q * 16;
  const int hw  = b * 512 + ((j0 * 2) ^ swz);                   // h write (rel. buffer)
  const float* bfp = bias_s + j0;
  const float* bgp = bias_s + 256 + j0;
  const float* bop = bias_s + 512 + j0;

  const f32x4 z4 = f32x4{0.f, 0.f, 0.f, 0.f};
  __syncthreads();

  for (int t = 0; t < TT; ++t) {
    char* zc = zb + (t & 1) * ZBUF;
    char* zn = zb + ((t + 1) & 1) * ZBUF;
    const bool more = (t + 1 < TT);

    f32x4 bf4 = *(const f32x4*)bfp;                  // L1-hit (prescaled bias)
    f32x4 bg4 = *(const f32x4*)bgp;
    f32x4 bo4 = *(const f32x4*)bop;

    // ---- xproj FIRST (r7 head placement): covers post-barrier LDS latency ----
    bf16x8 xf = cvt8(xa, xc);
    f32x4 acc0, acc1, acc2, acc3, acc4, acc5;
    {
      bf16x8 w0 = *(const bf16x8*)(wihl + (sbs[0] + m) * 64 + wro);
      bf16x8 w1 = *(const bf16x8*)(wihl + (sbs[1] + m) * 64 + wro);
      bf16x8 w2 = *(const bf16x8*)(wihl + (sbs[2] + m) * 64 + wro);
      bf16x8 w3 = *(const bf16x8*)(wihl + (sbs[3] + m) * 64 + wro);
      bf16x8 w4 = *(const bf16x8*)(wihl + (sbs[4] + m) * 64 + wro);
      bf16x8 w5 = *(const bf16x8*)(wihl + (sbs[5] + m) * 64 + wro);
      acc0 = __builtin_amdgcn_mfma_f32_16x16x32_bf16(w0, xf, z4, 0, 0, 0);
      acc1 = __builtin_amdgcn_mfma_f32_16x16x32_bf16(w1, xf, z4, 0, 0, 0);
      acc2 = __builtin_amdgcn_mfma_f32_16x16x32_bf16(w2, xf, z4, 0, 0, 0);
      acc3 = __builtin_amdgcn_mfma_f32_16x16x32_bf16(w3, xf, z4, 0, 0, 0);
      acc4 = __builtin_amdgcn_mfma_f32_16x16x32_bf16(w4, xf, z4, 0, 0, 0);
      acc5 = __builtin_amdgcn_mfma_f32_16x16x32_bf16(w5, xf, z4, 0, 0, 0);
    }

    // ---- issue x(t+1) loads now: covered by the full recurrent chain ----
    if (more) {
      xa = *(const f32x4*)xp;
      xc = *(const f32x4*)(xp + 4);
      xp += (size_t)BTOT * DIN;
    }

    // ---- recurrent chain: kk=0..6 from registers, kk=7 from LDS ----
    #pragma unroll
    for (int kk = 0; kk < 7; ++kk) {
      bf16x8 hf = *(const bf16x8*)(zc + hrb + ((kk * 64 + hq) ^ swz));
      acc0 = __builtin_amdgcn_mfma_f32_16x16x32_bf16(wr[0][kk], hf, acc0, 0, 0, 0);
      acc1 = __builtin_amdgcn_mfma_f32_16x16x32_bf16(wr[1][kk], hf, acc1, 0, 0, 0);
      acc2 = __builtin_amdgcn_mfma_f32_16x16x32_bf16(wr[2][kk], hf, acc2, 0, 0, 0);
      acc3 = __builtin_amdgcn_mfma_f32_16x16x32_bf16(wr[3][kk], hf, acc3, 0, 0, 0);
      acc4 = __builtin_amdgcn_mfma_f32_16x16x32_bf16(wr[4][kk], hf, acc4, 0, 0, 0);
      acc5 = __builtin_amdgcn_mfma_f32_16x16x32_bf16(wr[5][kk], hf, acc5, 0, 0, 0);
    }
    {   // kk = 7 from LDS
      bf16x8 hf = *(const bf16x8*)(zc + hrb + ((7 * 64 + hq) ^ swz));
      bf16x8 u0 = *(const bf16x8*)(whh7l + (sbs[0] + m) * 64 + wro);
      bf16x8 u1 = *(const bf16x8*)(whh7l + (sbs[1] + m) * 64 + wro);
      bf16x8 u2 = *(const bf16x8*)(whh7l + (sbs[2] + m) * 64 + wro);
      bf16x8 u3 = *(const bf16x8*)(whh7l + (sbs[3] + m) * 64 + wro);
      bf16x8 u4 = *(const bf16x8*)(whh7l + (sbs[4] + m) * 64 + wro);
      bf16x8 u5 = *(const bf16x8*)(whh7l + (sbs[5] + m) * 64 + wro);
      acc0 = __builtin_amdgcn_mfma_f32_16x16x32_bf16(u0, hf, acc0, 0, 0, 0);
      acc1 = __builtin_amdgcn_mfma_f32_16x16x32_bf16(u1, hf, acc1, 0, 0, 0);
      acc2 = __builtin_amdgcn_mfma_f32_16x16x32_bf16(u2, hf, acc2, 0, 0, 0);
      acc3 = __builtin_amdgcn_mfma_f32_16x16x32_bf16(u3, hf, acc3, 0, 0, 0);
      acc4 = __builtin_amdgcn_mfma_f32_16x16x32_bf16(u4, hf, acc4, 0, 0, 0);
      acc5 = __builtin_amdgcn_mfma_f32_16x16x32_bf16(u5, hf, acc5, 0, 0, 0);
    }

    // ---- elementwise (pre-activations prescaled by log2e; 2*log2e for g) ----
    float h0, h1, h2, h3;
    #pragma unroll
    for (int r = 0; r < 4; ++r) {
      float pf = (half ? acc3[r] : acc0[r]) + bf4[r];
      float pg = (half ? acc4[r] : acc1[r]) + bg4[r];
      float po = (half ? acc5[r] : acc2[r]) + bo4[r];
      float fg = __builtin_amdgcn_rcpf(1.0f + __builtin_amdgcn_exp2f(-pf));
      float gg = 1.0f - 2.0f * __builtin_amdgcn_rcpf(1.0f + __builtin_amdgcn_exp2f(pg));
      float og = __builtin_amdgcn_rcpf(1.0f + __builtin_amdgcn_exp2f(-po));
      float c  = fg * cst[r] + ig[r] * gg;
      cst[r] = c;
      float th = 1.0f - 2.0f * __builtin_amdgcn_rcpf(1.0f + __builtin_amdgcn_exp2f(c * (2.0f * L2E)));
      float hv = og * th;
      if (r == 0) h0 = hv; else if (r == 1) h1 = hv; else if (r == 2) h2 = hv; else h3 = hv;
    }
    unsigned pk0, pk1;
    asm("v_cvt_pk_bf16_f32 %0, %1, %2" : "=v"(pk0) : "v"(h0), "v"(h1));
    asm("v_cvt_pk_bf16_f32 %0, %1, %2" : "=v"(pk1) : "v"(h2), "v"(h3));
    u32x2 pk = u32x2{pk0, pk1};
    *(u32x2*)(zn + hw) = pk;                         // one ds_write_b64

    __syncthreads();
  }

  // ---- output: out[b] = sum_j h[b][j] * w_dense[j] + b_dense[0] ----
  if (tid < 64) {
    const char* hb = zb + (TT & 1) * ZBUF;           // TT=365 -> buffer 1
    int row = tid >> 3, seg = tid & 7;
    float sum = 0.0f;
    #pragma unroll
    for (int jj = 0; jj < 32; ++jj) {
      int j = seg * 32 + jj;
      unsigned short hu = *(const unsigned short*)(hb + row * 512 + ((j * 2) ^ (row << 4)));
      sum += bf2f(hu) * w_dense[j];
    }
    sum += __shfl_xor(sum, 1, 64);
    sum += __shfl_xor(sum, 2, 64);
    sum += __shfl_xor(sum, 4, 64);
    if (seg == 0) out[b0 + row] = sum + b_dense[0];
  }
}

extern "C" void kernel_launch(void* const* d_in, const int* in_sizes, int n_in,
                              void* d_out, int out_size, void* d_ws, size_t ws_size,
                              hipStream_t stream) {
  (void)in_sizes; (void)n_in; (void)out_size; (void)ws_size;
  const float* x_dd = (const float*)d_in[0];
  const float* x_s  = (const float*)d_in[1];
  const float* wih  = (const float*)d_in[2];
  const float* whh  = (const float*)d_in[3];
  const float* bias = (const float*)d_in[4];
  const float* w_in = (const float*)d_in[5];
  const float* b_in = (const float*)d_in[6];
  const float* w_d  = (const float*)d_in[7];
  const float* b_d  = (const float*)d_in[8];
  float* out = (float*)d_out;
  unsigned char* ws = (unsigned char*)d_ws;

  unsigned short* whh_bf = (unsigned short*)ws;
  unsigned short* wih_bf = (unsigned short*)(ws + WS_WIH);
  float*          bias_s = (float*)(ws + WS_BIAS);

  prep_kernel<<<128, 256, 0, stream>>>(whh, wih, bias, whh_bf, wih_bf, bias_s);
  ealstm_kernel<<<BTOT / 8, BLOCK, 0, stream>>>(
      x_dd, x_s, w_in, b_in, w_d, b_d, whh_bf, wih_bf, bias_s, out);
}